// Round 8
// baseline (58.562 us; speedup 1.0000x reference)
//
#include <hip/hip_runtime.h>

#define HEIGHT 8
#define NXCD 8

// ---------------- prep: per-box params + width output + per-image bucket ----------------
// params[2m]   = {cx, cy, s, (width-1)/2}
// params[2m+1] = {ca, sa, ceil(width), image_index_bits}
// perm[b*M + rank] = m for boxes of image b; cnt[b] = count.
__global__ void __launch_bounds__(256)
prep_kernel(const float* __restrict__ boxes,
            const int* __restrict__ box_indices,
            float4* __restrict__ params,
            int* __restrict__ perm,
            int* __restrict__ cnt,
            float* __restrict__ width_out,
            int M, int mw)
{
    const int m = blockIdx.x * 256 + threadIdx.x;
    if (m >= M) return;
    const float x1  = boxes[m * 5 + 0];
    const float y1  = boxes[m * 5 + 1];
    const float x2  = boxes[m * 5 + 2];
    const float y2  = boxes[m * 5 + 3];
    const float ang = boxes[m * 5 + 4];
    const float bwd = x2 - x1, bhd = y2 - y1;
    const float width = (float)HEIGHT * bwd / bhd;   // same assoc as reference
    const int b = box_indices[m];
    params[2 * m]     = make_float4((x1 + x2) * 0.5f, (y1 + y2) * 0.5f,
                                    bhd / (float)HEIGHT, (width - 1.0f) * 0.5f);
    params[2 * m + 1] = make_float4(cosf(ang), sinf(ang), ceilf(width),
                                    __int_as_float(b));
    width_out[m] = (float)mw - width;
    const int rank = atomicAdd(&cnt[b], 1);
    perm[b * M + rank] = m;
}

// ---------------- phased sampler: per-XCD L2 warming + L2-hit gathers ----------------
// Phase p, XCD x (= blockIdx&7 under round-robin dispatch) handles image 8p+x
// (3.1 MB < 4 MiB per-XCD L2). Each block stream-reads its chunk of the image
// (sequential compulsory misses -> fills this XCD's L2), then samples only
// boxes of that image: scattered reads become L2 hits (~200cy vs ~900cy cold).
// Crop stores are nontemporal so 49 MB of writes doesn't evict the image.
__global__ void __launch_bounds__(512)
phase_kernel(const float* __restrict__ images,
             const float4* __restrict__ params,
             const int* __restrict__ perm,
             const int* __restrict__ cnt,
             float* __restrict__ crops,
             int mw, int Himg, int Wimg, int M, int phase, int N)
{
    const int x   = blockIdx.x & (NXCD - 1);
    const int r   = blockIdx.x >> 3;
    const int nbx = (int)gridDim.x >> 3;
    const int tid = threadIdx.x;
    const int img_idx = phase * NXCD + x;
    if (img_idx >= N) return;

    const size_t imgsz = (size_t)Himg * Wimg * 3;
    const float* img = images + (size_t)img_idx * imgsz;

    // --- warm this XCD's L2 with my chunk of the image (sequential) ---
    {
        const float4* im4 = (const float4*)img;
        const int n4    = (int)(imgsz >> 2);
        const int chunk = (n4 + nbx - 1) / nbx;
        const int kend  = min((r + 1) * chunk, n4);
        float acc = 0.0f;
        for (int k = r * chunk + tid; k < kend; k += 512) {
            const float4 v = im4[k];
            acc += v.x + v.y + v.z + v.w;
        }
        asm volatile("" :: "v"(acc));   // keep warming loads live
    }

    // --- sample all boxes of this image assigned to this block ---
    const int nc    = cnt[img_idx];
    const int nsamp = HEIGHT * mw;
    for (int p = r; p < nc; p += nbx) {
        const int m = perm[img_idx * M + p];
        const float4 pA = params[2 * m];       // cx, cy, s, (width-1)/2
        const float4 pB = params[2 * m + 1];   // ca, sa, ceil(width), img-bits
        const float cx = pA.x, cy = pA.y, s = pA.z, px = pA.w;
        const float ca = pB.x, sa = pB.y, wlim = pB.z;
        float* oblk = crops + (size_t)m * nsamp * 3;

        for (int idx = tid; idx < nsamp; idx += 512) {
            int i, j;
            if (mw == 64) { i = idx >> 6; j = idx & 63; }
            else          { i = idx / mw; j = idx - i * mw; }

            const float dx = s * ((float)j - px);
            const float dy = s * ((float)i - ((float)HEIGHT - 1.0f) * 0.5f);
            const float sx = cx + ca * dx - sa * dy;
            const float sy = cy + sa * dx + ca * dy;

            float v0 = 0.0f, v1 = 0.0f, v2 = 0.0f;
            const bool valid = ((float)j < wlim) &&
                               (sx >= 0.0f) && (sx <= (float)(Wimg - 1)) &&
                               (sy >= 0.0f) && (sy <= (float)(Himg - 1));
            if (valid) {
                const float x0 = floorf(sx);
                const float y0 = floorf(sy);
                const int x0i = (int)x0;
                const int y0i = (int)y0;
                const int xb  = min(x0i, Wimg - 2);
                const int yb  = min(y0i, Himg - 2);
                // clamped => the clamped texel's weight is exactly 0, so shift
                // full weight onto the in-segment element (indices stay static)
                const float fx = (x0i == xb) ? (sx - x0) : 1.0f;
                const float fy = (y0i == yb) ? (sy - y0) : 1.0f;

                const float* r0 = img + ((size_t)yb * Wimg + xb) * 3;
                const float* r1 = r0 + (size_t)Wimg * 3;
                float s0[6], s1[6];
                __builtin_memcpy(s0, r0, 24);   // 2 px x 3 ch, row yb
                __builtin_memcpy(s1, r1, 24);   // 2 px x 3 ch, row yb+1

                const float w00 = (1.0f - fx) * (1.0f - fy);
                const float w01 = fx * (1.0f - fy);
                const float w10 = (1.0f - fx) * fy;
                const float w11 = fx * fy;

                v0 = s0[0] * w00 + s0[3] * w01 + s1[0] * w10 + s1[3] * w11;
                v1 = s0[1] * w00 + s0[4] * w01 + s1[1] * w10 + s1[4] * w11;
                v2 = s0[2] * w00 + s0[5] * w01 + s1[2] * w10 + s1[5] * w11;
            }
            float* o = oblk + (size_t)idx * 3;
            __builtin_nontemporal_store(v0, o + 0);
            __builtin_nontemporal_store(v1, o + 1);
            __builtin_nontemporal_store(v2, o + 2);
        }
    }
}

extern "C" void kernel_launch(void* const* d_in, const int* in_sizes, int n_in,
                              void* d_out, int out_size, void* d_ws, size_t ws_size,
                              hipStream_t stream) {
    const float* images      = (const float*)d_in[0];
    const float* boxes       = (const float*)d_in[2];
    const int*   box_indices = (const int*)d_in[3];

    const int M  = in_sizes[3];                       // 8192 boxes
    const int mw = (out_size - M) / (M * HEIGHT * 3); // max_width (=64)
    const int Himg = 512, Wimg = 512;
    const int N  = in_sizes[0] / (Himg * Wimg * 3);   // 16 images

    float* crops     = (float*)d_out;
    float* width_out = crops + (size_t)M * HEIGHT * mw * 3;

    // workspace: params (2M float4) | perm (N*M int) | cnt (N int)
    float4* params = (float4*)d_ws;
    int*    perm   = (int*)((char*)d_ws + (size_t)2 * M * sizeof(float4));
    int*    cnt    = perm + (size_t)N * M;

    hipMemsetAsync(cnt, 0, N * sizeof(int), stream);
    prep_kernel<<<(M + 255) / 256, 256, 0, stream>>>(
        boxes, box_indices, params, perm, cnt, width_out, M, mw);

    const int phases = (N + NXCD - 1) / NXCD;         // 2 for N=16
    for (int p = 0; p < phases; ++p) {
        phase_kernel<<<NXCD * 128, 512, 0, stream>>>(
            images, params, perm, cnt, crops, mw, Himg, Wimg, M, p, N);
    }
}

// Round 9
// 43.312 us; speedup vs baseline: 1.3521x; 1.3521x over previous
//
#include <hip/hip_runtime.h>

#define HEIGHT 8

// ---------------- prep: per-box params + width output ----------------
// params[2m]   = {cx, cy, s, (width-1)/2}
// params[2m+1] = {ca, sa, ceil(width), image_index_bits}
__global__ void __launch_bounds__(256)
prep_kernel(const float* __restrict__ boxes,
            const int* __restrict__ box_indices,
            float4* __restrict__ params,
            float* __restrict__ width_out,
            int M, int mw)
{
    const int m = blockIdx.x * 256 + threadIdx.x;
    if (m >= M) return;
    const float x1  = boxes[m * 5 + 0];
    const float y1  = boxes[m * 5 + 1];
    const float x2  = boxes[m * 5 + 2];
    const float y2  = boxes[m * 5 + 3];
    const float ang = boxes[m * 5 + 4];
    const float bwd = x2 - x1, bhd = y2 - y1;
    const float width = (float)HEIGHT * bwd / bhd;   // same assoc as reference
    params[2 * m]     = make_float4((x1 + x2) * 0.5f, (y1 + y2) * 0.5f,
                                    bhd / (float)HEIGHT, (width - 1.0f) * 0.5f);
    params[2 * m + 1] = make_float4(cosf(ang), sinf(ang), ceilf(width),
                                    __int_as_float(box_indices[m]));
    width_out[m] = (float)mw - width;
}

// ---------------- MLP sampler: 8 samples/thread, all loads in flight ----------------
// 4 boxes per 256-thread block; thread t handles sample (t + 256*c) of box k
// for (k,c) in 4x2. All 8 samples' texel loads (32 vmem instrs) are issued
// BEFORE any consume; an asm-volatile liveness barrier naming one element per
// load instruction prevents the register minimizer from re-serializing them
// (R5's attempt collapsed to VGPR=16 => loads sunk to uses => test void).
__global__ void __launch_bounds__(256)
roi_mlp_kernel(const float* __restrict__ images,
               const float4* __restrict__ params,
               float* __restrict__ crops,
               int Himg, int Wimg, int M)
{
    const int t  = threadIdx.x;
    const size_t imgsz = (size_t)Himg * Wimg * 3;

    int   mb[4];
    float cx[4], cy[4], ss[4], px[4], ca[4], sa[4], wl[4];
    const float* img[4];
    #pragma unroll
    for (int k = 0; k < 4; ++k) {
        mb[k] = min(blockIdx.x * 4 + k, M - 1);   // tail: duplicate last box (benign)
        const float4 pA = params[2 * mb[k]];
        const float4 pB = params[2 * mb[k] + 1];
        cx[k] = pA.x; cy[k] = pA.y; ss[k] = pA.z; px[k] = pA.w;
        ca[k] = pB.x; sa[k] = pB.y; wl[k] = pB.z;
        img[k] = images + (size_t)__float_as_int(pB.w) * imgsz;
    }

    float S0[8][6], S1[8][6];   // texel rows per sample (const-indexed after unroll)
    float fx[8], fy[8];
    bool  vv[8];

    // ---- phase 1: address calc + issue ALL loads ----
    #pragma unroll
    for (int q = 0; q < 8; ++q) {
        const int k   = q >> 1;
        const int idx = t + 256 * (q & 1);
        const int i   = idx >> 6;            // mw==64 fast path
        const int j   = idx & 63;

        const float dx = ss[k] * ((float)j - px[k]);
        const float dy = ss[k] * ((float)i - ((float)HEIGHT - 1.0f) * 0.5f);
        const float sx = cx[k] + ca[k] * dx - sa[k] * dy;
        const float sy = cy[k] + sa[k] * dx + ca[k] * dy;

        vv[q] = ((float)j < wl[k]) &&
                (sx >= 0.0f) && (sx <= (float)(Wimg - 1)) &&
                (sy >= 0.0f) && (sy <= (float)(Himg - 1));
        fx[q] = 0.0f; fy[q] = 0.0f;
        #pragma unroll
        for (int e = 0; e < 6; ++e) { S0[q][e] = 0.0f; S1[q][e] = 0.0f; }

        if (vv[q]) {
            const float x0 = floorf(sx);
            const float y0 = floorf(sy);
            const int x0i = (int)x0;
            const int y0i = (int)y0;
            const int xb  = min(x0i, Wimg - 2);
            const int yb  = min(y0i, Himg - 2);
            // clamped => clamped texel's weight is exactly 0; fold into fx/fy
            fx[q] = (x0i == xb) ? (sx - x0) : 1.0f;
            fy[q] = (y0i == yb) ? (sy - y0) : 1.0f;
            const float* r0 = img[k] + ((size_t)yb * Wimg + xb) * 3;
            const float* r1 = r0 + (size_t)Wimg * 3;
            __builtin_memcpy(&S0[q][0], r0, 24);
            __builtin_memcpy(&S1[q][0], r1, 24);
        }
    }

    // ---- liveness barrier: one element per vmem instruction (x4 and x2 parts,
    // both rows, all 8 samples) => all 32 loads issued before this point ----
    asm volatile("" ::
        "v"(S0[0][0]), "v"(S0[0][4]), "v"(S1[0][0]), "v"(S1[0][4]),
        "v"(S0[1][0]), "v"(S0[1][4]), "v"(S1[1][0]), "v"(S1[1][4]),
        "v"(S0[2][0]), "v"(S0[2][4]), "v"(S1[2][0]), "v"(S1[2][4]),
        "v"(S0[3][0]), "v"(S0[3][4]), "v"(S1[3][0]), "v"(S1[3][4]));
    asm volatile("" ::
        "v"(S0[4][0]), "v"(S0[4][4]), "v"(S1[4][0]), "v"(S1[4][4]),
        "v"(S0[5][0]), "v"(S0[5][4]), "v"(S1[5][0]), "v"(S1[5][4]),
        "v"(S0[6][0]), "v"(S0[6][4]), "v"(S1[6][0]), "v"(S1[6][4]),
        "v"(S0[7][0]), "v"(S0[7][4]), "v"(S1[7][0]), "v"(S1[7][4]));

    // ---- phase 2: consume + store ----
    #pragma unroll
    for (int q = 0; q < 8; ++q) {
        const int k   = q >> 1;
        const int idx = t + 256 * (q & 1);
        float v0 = 0.0f, v1 = 0.0f, v2 = 0.0f;
        if (vv[q]) {
            const float w00 = (1.0f - fx[q]) * (1.0f - fy[q]);
            const float w01 = fx[q] * (1.0f - fy[q]);
            const float w10 = (1.0f - fx[q]) * fy[q];
            const float w11 = fx[q] * fy[q];
            v0 = S0[q][0] * w00 + S0[q][3] * w01 + S1[q][0] * w10 + S1[q][3] * w11;
            v1 = S0[q][1] * w00 + S0[q][4] * w01 + S1[q][1] * w10 + S1[q][4] * w11;
            v2 = S0[q][2] * w00 + S0[q][5] * w01 + S1[q][2] * w10 + S1[q][5] * w11;
        }
        float* o = crops + ((size_t)mb[k] * (HEIGHT * 64) + idx) * 3;
        o[0] = v0; o[1] = v1; o[2] = v2;
    }
}

// ---------------- generic fallback (R4 structure) for mw != 64 ----------------
__global__ void __launch_bounds__(512)
roi_generic_kernel(const float* __restrict__ images,
                   const float4* __restrict__ params,
                   float* __restrict__ crops,
                   int mw, int Himg, int Wimg)
{
    const int m   = blockIdx.x;
    const int tid = threadIdx.x;
    const int nsamp = HEIGHT * mw;
    const float4 pA = params[2 * m];
    const float4 pB = params[2 * m + 1];
    const float* img = images + (size_t)__float_as_int(pB.w) * (size_t)Himg * Wimg * 3;
    float* oblk = crops + (size_t)m * nsamp * 3;

    for (int idx = tid; idx < nsamp; idx += blockDim.x) {
        const int i = idx / mw, j = idx - i * mw;
        const float dx = pA.z * ((float)j - pA.w);
        const float dy = pA.z * ((float)i - ((float)HEIGHT - 1.0f) * 0.5f);
        const float sx = pA.x + pB.x * dx - pB.y * dy;
        const float sy = pA.y + pB.y * dx + pB.x * dy;
        float v0 = 0, v1 = 0, v2 = 0;
        const bool valid = ((float)j < pB.z) &&
                           (sx >= 0.0f) && (sx <= (float)(Wimg - 1)) &&
                           (sy >= 0.0f) && (sy <= (float)(Himg - 1));
        if (valid) {
            const float x0 = floorf(sx), y0 = floorf(sy);
            const int x0i = (int)x0, y0i = (int)y0;
            const int xb = min(x0i, Wimg - 2), yb = min(y0i, Himg - 2);
            const float fx = (x0i == xb) ? (sx - x0) : 1.0f;
            const float fy = (y0i == yb) ? (sy - y0) : 1.0f;
            const float* r0 = img + ((size_t)yb * Wimg + xb) * 3;
            const float* r1 = r0 + (size_t)Wimg * 3;
            float s0[6], s1[6];
            __builtin_memcpy(s0, r0, 24);
            __builtin_memcpy(s1, r1, 24);
            const float w00 = (1.0f - fx) * (1.0f - fy);
            const float w01 = fx * (1.0f - fy);
            const float w10 = (1.0f - fx) * fy;
            const float w11 = fx * fy;
            v0 = s0[0] * w00 + s0[3] * w01 + s1[0] * w10 + s1[3] * w11;
            v1 = s0[1] * w00 + s0[4] * w01 + s1[1] * w10 + s1[4] * w11;
            v2 = s0[2] * w00 + s0[5] * w01 + s1[2] * w10 + s1[5] * w11;
        }
        float* o = oblk + (size_t)idx * 3;
        o[0] = v0; o[1] = v1; o[2] = v2;
    }
}

extern "C" void kernel_launch(void* const* d_in, const int* in_sizes, int n_in,
                              void* d_out, int out_size, void* d_ws, size_t ws_size,
                              hipStream_t stream) {
    const float* images      = (const float*)d_in[0];
    const float* boxes       = (const float*)d_in[2];
    const int*   box_indices = (const int*)d_in[3];

    const int M  = in_sizes[3];                       // 8192 boxes
    const int mw = (out_size - M) / (M * HEIGHT * 3); // max_width (=64)
    const int Himg = 512, Wimg = 512;

    float* crops     = (float*)d_out;
    float* width_out = crops + (size_t)M * HEIGHT * mw * 3;

    float4* params = (float4*)d_ws;                   // 2*M float4

    prep_kernel<<<(M + 255) / 256, 256, 0, stream>>>(
        boxes, box_indices, params, width_out, M, mw);

    if (mw == 64) {
        roi_mlp_kernel<<<(M + 3) / 4, 256, 0, stream>>>(
            images, params, crops, Himg, Wimg, M);
    } else {
        roi_generic_kernel<<<M, 512, 0, stream>>>(
            images, params, crops, mw, Himg, Wimg);
    }
}